// Round 5
// baseline (1253.687 us; speedup 1.0000x reference)
//
#include <hip/hip_runtime.h>

#define T_STEPS 1024
#define B_SEQ   4096

typedef float v2f __attribute__((ext_vector_type(2)));
typedef float v4f __attribute__((ext_vector_type(4)));

// DPP row_ror:N within 16-lane rows: dst[i] = src[(i-N)&15]
#define ROR(x, N) __int_as_float(__builtin_amdgcn_mov_dpp(__float_as_int(x), 0x120 + (N), 0xF, 0xF, false))
// ds_swizzle BitMode: lane' = lane ^ 16  -> offset (0x10<<10)|0x1F
#define SWZ16(x) __int_as_float(__builtin_amdgcn_ds_swizzle(__float_as_int(x), 0x401F))

__device__ __forceinline__ v4f pkfma4(v4f a, v4f b, v4f c) {
    return __builtin_elementwise_fma(a, b, c);  // lowers to 2x v_pk_fma_f32
}

// tanh(x) = 1 - 2/(e^{2x}+1). No clamp: exp2 overflow->inf->rcp->0->+1 exact;
// underflow->0->rcp(1)=1->-1 exact.
__device__ __forceinline__ float tanh_fast(float x) {
    float e = __builtin_amdgcn_exp2f(x * 2.88539008177793f);
    return fmaf(-2.0f, __builtin_amdgcn_rcpf(e + 1.0f), 1.0f);
}

// Runtime dtype sniff (insurance; rounds 1-3 proved inputs are f32).
__device__ __forceinline__ bool sniff_is_bf16(const void* p) {
    unsigned short h = ((const unsigned short*)p)[threadIdx.x & 63];
    union { unsigned u; float f; } c; c.u = ((unsigned)h) << 16;
    float f = fabsf(c.f);
    bool bad = !(f <= 1e4f) || (f != 0.0f && f < 1e-10f);
    return __ballot(bad) == 0ULL;
}

__device__ __forceinline__ float ldf(const void* p, long long i, bool isbf) {
    if (isbf) {
        unsigned short h = ((const unsigned short*)p)[i];
        union { unsigned u; float f; } c; c.u = ((unsigned)h) << 16;
        return c.f;
    }
    return ((const float*)p)[i];
}

// 64-thread single-wave blocks; 2 sequences per block.
// lane = seq_local*32 + net*16 + j
__global__ __launch_bounds__(64, 2) void reac_rk4_kernel(
    const void* __restrict__ u_,     const void* __restrict__ xz0_,
    const void* __restrict__ r1_W0_, const void* __restrict__ r1_b0_,
    const void* __restrict__ r1_W1_, const void* __restrict__ r1_b1_,
    const void* __restrict__ r1_W2_, const void* __restrict__ r1_b2_,
    const void* __restrict__ r2_W0_, const void* __restrict__ r2_b0_,
    const void* __restrict__ r2_W1_, const void* __restrict__ r2_b1_,
    const void* __restrict__ r2_W2_, const void* __restrict__ r2_b2_,
    const void* __restrict__ ymean_, const void* __restrict__ ystd_,
    const void* __restrict__ umean_, const void* __restrict__ ustd_,
    float* __restrict__ out)
{
    // h1 staging: one float per lane; single wave per block, per-wave in-order
    // DS semantics -> no __syncthreads needed anywhere.
    __shared__ __align__(16) float shm[64];

    const int tid = threadIdx.x;
    const int j   = tid & 15;
    const int net = (tid >> 4) & 1;
    const long long b = (long long)blockIdx.x * 2 + (tid >> 5);

    const bool vW = sniff_is_bf16(r1_W1_);
    const bool vU = sniff_is_bf16(u_);
    const bool vX = sniff_is_bf16(xz0_);

    // ---- per-lane weights ----
    float w0a, w0b, b0;
    if (net) { w0a = ldf(r2_W0_, j, vW); w0b = ldf(r2_W0_, 16 + j, vW); b0 = ldf(r2_b0_, j, vW); }
    else     { w0a = ldf(r1_W0_, j, vW); w0b = 0.0f;                    b0 = ldf(r1_b0_, j, vW); }

    // natural-order layer-2 column j as 4 quads: w4[q][i] = W1[4q+i][j]
    const void* W1 = net ? r2_W1_ : r1_W1_;
    v4f w4[4];
    #pragma unroll
    for (int q = 0; q < 4; ++q)
        #pragma unroll
        for (int i = 0; i < 4; ++i)
            w4[q][i] = ldf(W1, (4 * q + i) * 16 + j, vW);
    const float b1v = ldf(net ? r2_b1_ : r1_b1_, j, vW);

    const float Camean = ldf(ymean_, 0, vW), Cbmean = ldf(ymean_, 1, vW);
    const float Castd  = ldf(ystd_,  0, vW), Cbstd  = ldf(ystd_,  1, vW);
    const float um     = ldf(umean_, 0, vW), us     = ldf(ustd_,  0, vW);
    const float invCastd = 1.0f / Castd, invCbstd = 1.0f / Cbstd;

    // fold output std into layer-3 weights
    const float ostd = net ? Cbstd : Castd;
    const float w2s  = ldf(net ? r2_W2_ : r1_W2_, j, vW) * ostd;
    const float b2s  = ldf(net ? r2_b2_ : r1_b2_, 0, vW) * ostd;

    // ---- state ----
    v2f   Cab = { ldf(xz0_, b * 3 + 0, vX), ldf(xz0_, b * 3 + 1, vX) };
    float Cc  =   ldf(xz0_, b * 3 + 2, vX);

    // ---- output lanes: c=0,1 -> yseq; c=2,3,4 -> xseq ----
    const int  c      = tid & 31;
    const bool active = (c < 5);
    float* sp;
    int sstr;
    if (c < 2) { sp = out + b * (T_STEPS * 2) + c;                                        sstr = 2; }
    else       { sp = out + (long long)B_SEQ * T_STEPS * 2 + b * (T_STEPS * 3) + (c - 2); sstr = 3; }
    const bool selA = (c == 0) | (c == 2);
    const bool selB = (c == 1) | (c == 3);

    const long long ubase = b * T_STEPS;
    float ut = ldf(u_, ubase, vU);

    const v2f HALF2  = { 0.5f, 0.5f };
    const v2f TWO2   = { 2.0f, 2.0f };
    const v2f SIXTH2 = { 1.0f / 6.0f, 1.0f / 6.0f };
    const v2f STD2   = { Castd, Cbstd };
    const v2f MEAN2  = { Camean, Cbmean };
    const v2f ISTD2  = { invCastd, invCbstd };

    // group-base pointer for the 16-value broadcast gather
    const v4f* gblk = (const v4f*)(shm + (tid & 48));
    float* gwr = shm + tid;

    auto fxu = [&](v2f xab, float xc, float fCaf, v2f& kab, float& kc) {
        // layer 1
        float A0 = net ? xab.y : xab.x;
        float h1 = tanh_fast(fmaf(w0a, A0, fmaf(w0b, xc, b0)));

        // stage h1, gather all 16 of this group's h values (broadcast reads)
        *gwr = h1;
        v4f hq0 = gblk[0], hq1 = gblk[1], hq2 = gblk[2], hq3 = gblk[3];

        // layer 2: 4x v4f fma = 8 v_pk_fma_f32, zero transport movs
        v4f acc = { b1v, 0.0f, 0.0f, 0.0f };
        acc = pkfma4(hq0, w4[0], acc);
        acc = pkfma4(hq1, w4[1], acc);
        acc = pkfma4(hq2, w4[2], acc);
        acc = pkfma4(hq3, w4[3], acc);
        float h2 = tanh_fast((acc.x + acc.y) + (acc.z + acc.w));

        // layer 3: cyclic DPP reduce over the 16-lane net group (pre-scaled)
        float p = h2 * w2s;
        p += ROR(p, 8); p += ROR(p, 4); p += ROR(p, 2); p += ROR(p, 1);
        float ov    = p + b2s;
        float other = SWZ16(ov);                  // r1 <-> r2 exchange
        float r1v = net ? other : ov;             // = r1 * Castd
        float r2v = net ? ov : other;             // = r2 * Cbstd

        // physics
        v2f   Cab_p = __builtin_elementwise_fma(xab, STD2, MEAN2);
        float Cc_p  = fmaf(xc, Cbstd, Cbmean);
        float dCa   = fmaf(-0.1f, Cab_p.x, fCaf) - r1v;
        float dCb   = fmaf(-0.1f, Cab_p.y, fmaf(-3.0f, r2v, r1v));
        float dCc   = fmaf(-0.1f, Cc_p, r2v);
        v2f d; d.x = dCa; d.y = dCb;
        kab = d * ISTD2;
        kc  = dCc * invCbstd;
    };

    for (int t = 0; t < T_STEPS; ++t) {
        float v = selA ? Cab.x : (selB ? Cab.y : Cc);
        if (active) { *sp = v; sp += sstr; }
        if (t == T_STEPS - 1) break;

        float utn  = ldf(u_, ubase + t + 1, vU);
        float fCaf = 0.1f * fmaf(ut, us, um);

        v2f k1ab, k2ab, k3ab, k4ab;
        float k1c, k2c, k3c, k4c;

        fxu(Cab, Cc, fCaf, k1ab, k1c);
        fxu(__builtin_elementwise_fma(HALF2, k1ab, Cab), fmaf(0.5f, k1c, Cc), fCaf, k2ab, k2c);
        fxu(__builtin_elementwise_fma(HALF2, k2ab, Cab), fmaf(0.5f, k2c, Cc), fCaf, k3ab, k3c);
        fxu(Cab + k3ab, Cc + k3c, fCaf, k4ab, k4c);

        v2f   sab = __builtin_elementwise_fma(TWO2, k2ab + k3ab, k1ab) + k4ab;
        float sc  = fmaf(2.0f, k2c + k3c, k1c) + k4c;
        Cab = __builtin_elementwise_fma(SIXTH2, sab, Cab);
        Cc  = fmaf(1.0f / 6.0f, sc, Cc);
        ut  = utn;
    }
}

extern "C" void kernel_launch(void* const* d_in, const int* in_sizes, int n_in,
                              void* d_out, int out_size, void* d_ws, size_t ws_size,
                              hipStream_t stream) {
    (void)in_sizes; (void)n_in; (void)out_size; (void)d_ws; (void)ws_size;
    dim3 grid(B_SEQ / 2);
    dim3 block(64);
    reac_rk4_kernel<<<grid, block, 0, stream>>>(
        d_in[0],  d_in[1],
        d_in[2],  d_in[3],  d_in[4],  d_in[5],  d_in[6],  d_in[7],
        d_in[8],  d_in[9],  d_in[10], d_in[11], d_in[12], d_in[13],
        d_in[14], d_in[15], d_in[16], d_in[17],
        (float*)d_out);
}